// Round 8
// baseline (273.654 us; speedup 1.0000x reference)
//
#include <hip/hip_runtime.h>

// NodeFeatures: out = relu(x@Wu^T + bu + mask @ (x@Wv^T + bv))
// B=8, N=2048, D=128.
// R7 counters: k2 = 105us, 762 GB/s (9.5%), MfmaUtil 3%, Occ 18% -> LATENCY-
// bound. Root cause: Vt (bfv) loads issued inside COMPUTE right before MFMA;
// in-order vmcnt => waiting on them drains the 3-deep mask prefetch queue
// (de-facto vmcnt(0) every phase, full HBM round-trip per COMPUTE).
// R8: register-prefetch BOTH mask (sA/sB/sC) and Vt (vA/vB/vC) 3 steps ahead;
// no load is issued between a prefetch and its use => compiler emits counted
// vmcnt(~24), pipeline stays filled. All array indices literal (rule #20).

typedef __bf16 bf16x8 __attribute__((ext_vector_type(8)));
typedef __bf16 bf16x4 __attribute__((ext_vector_type(4)));
typedef float  f32x4  __attribute__((ext_vector_type(4)));

#define MFMA16(A, B, C) __builtin_amdgcn_mfma_f32_16x16x32_bf16(A, B, C, 0, 0, 0)

static __device__ __forceinline__ bf16x8 cvt8(const float* __restrict__ p) {
    float4 a = *(const float4*)p;
    float4 b = *(const float4*)(p + 4);
    bf16x8 v;
    v[0] = (__bf16)a.x; v[1] = (__bf16)a.y; v[2] = (__bf16)a.z; v[3] = (__bf16)a.w;
    v[4] = (__bf16)b.x; v[5] = (__bf16)b.y; v[6] = (__bf16)b.z; v[7] = (__bf16)b.w;
    return v;
}

static __device__ __forceinline__ bf16x8 pack8(const float4 a, const float4 b) {
    bf16x8 v;
    v[0] = (__bf16)a.x; v[1] = (__bf16)a.y; v[2] = (__bf16)a.z; v[3] = (__bf16)a.w;
    v[4] = (__bf16)b.x; v[5] = (__bf16)b.y; v[6] = (__bf16)b.z; v[7] = (__bf16)b.w;
    return v;
}

// ---------------------------------------------------------------------------
// Kernel 1 (unchanged): Uxb = bf16(x@Wu^T+bu); Vt[b][e][n] = bf16(x@Wv^T+bv)
// D-frag (m89-verified): col = lane&15, row = (lane>>4)*4 + reg.
// ---------------------------------------------------------------------------
__global__ __launch_bounds__(256) void k1_uv(
    const float* __restrict__ x,  const float* __restrict__ Wu,
    const float* __restrict__ bu, const float* __restrict__ Wv,
    const float* __restrict__ bv,
    __bf16* __restrict__ Uxb, __bf16* __restrict__ Vt)
{
    const int tid  = threadIdx.x;
    const int wv   = tid >> 6;
    const int lane = tid & 63;
    const int l16  = lane & 15;
    const int l4   = lane >> 4;
    const int row0 = blockIdx.x * 64;
    const int e0   = wv * 32;

    const f32x4 zero = {0.f, 0.f, 0.f, 0.f};
    f32x4 acc[4][4];
    #pragma unroll
    for (int mt = 0; mt < 4; ++mt)
        #pragma unroll
        for (int f = 0; f < 4; ++f) acc[mt][f] = zero;

    #pragma unroll
    for (int kf = 0; kf < 4; ++kf) {
        const int ko = kf * 32 + l4 * 8;
        bf16x8 af[4], bf[4];
        #pragma unroll
        for (int mt = 0; mt < 4; ++mt)
            af[mt] = cvt8(x + (size_t)(row0 + mt * 16 + l16) * 128 + ko);
        bf[0] = cvt8(Wu + (size_t)(e0 +      l16) * 128 + ko);
        bf[1] = cvt8(Wu + (size_t)(e0 + 16 + l16) * 128 + ko);
        bf[2] = cvt8(Wv + (size_t)(e0 +      l16) * 128 + ko);
        bf[3] = cvt8(Wv + (size_t)(e0 + 16 + l16) * 128 + ko);
        #pragma unroll
        for (int mt = 0; mt < 4; ++mt)
            #pragma unroll
            for (int f = 0; f < 4; ++f)
                acc[mt][f] = MFMA16(af[mt], bf[f], acc[mt][f]);
    }

    const int bidx = row0 >> 11;
    #pragma unroll
    for (int f = 0; f < 4; ++f) {
        const int e    = e0 + (f & 1) * 16 + l16;
        const bool isV = (f >= 2);
        const float bias = isV ? bv[e] : bu[e];
        #pragma unroll
        for (int mt = 0; mt < 4; ++mt) {
            if (!isV) {
                #pragma unroll
                for (int r = 0; r < 4; ++r) {
                    const int row = row0 + mt * 16 + l4 * 4 + r;
                    Uxb[(size_t)row * 128 + e] = (__bf16)(acc[mt][f][r] + bias);
                }
            } else {
                const int nbase = (row0 & 2047) + mt * 16 + l4 * 4;
                bf16x4 pk;
                #pragma unroll
                for (int r = 0; r < 4; ++r) pk[r] = (__bf16)(acc[mt][f][r] + bias);
                *(bf16x4*)(Vt + ((size_t)bidx * 128 + e) * 2048 + nbase) = pk;
            }
        }
    }
}

// ---------------------------------------------------------------------------
// Kernel 2 (R8): barrier-free, LDS-free; BOTH operand streams register-
// prefetched 3 K-steps ahead. Per phase: consume {sX,vX} (loaded 3 phases
// ago) -> issue {sX,vX} loads for ks+3. Compiler dataflow waitcnt = counted
// vmcnt (24 newer loads stay in flight). Grid 512, XCD-swizzled.
// ---------------------------------------------------------------------------
__global__ __launch_bounds__(256) void k2_agg(
    const float* __restrict__ mask,
    const __bf16* __restrict__ Vt,
    const __bf16* __restrict__ Uxb,
    float* __restrict__ out)
{
    const int bid = blockIdx.x;                   // 0..511
    const int lb  = (bid & 7) * 64 + (bid >> 3);  // bijective XCD swizzle (512 = 8*64)
    const int b   = lb >> 6;
    const int m0  = (lb & 63) * 32;

    const int tid  = threadIdx.x;
    const int wv   = tid >> 6;
    const int lane = tid & 63;
    const int l16  = lane & 15;
    const int l4   = lane >> 4;

    // A rows for this lane: mf=0 -> m0+l16, mf=1 -> m0+16+l16; k base = l4*8
    const float* r0 = mask + ((size_t)b * 2048 + m0 + l16) * 2048 + l4 * 8;
    const float* r1 = r0 + (size_t)16 * 2048;
    // B operand base for this wave/lane (Vt is [128e][2048n] per batch)
    const __bf16* vb = Vt + ((size_t)b * 128 + wv * 32 + l16) * 2048 + l4 * 8;

    const f32x4 zero = {0.f, 0.f, 0.f, 0.f};
    f32x4 acc[2][2];
    acc[0][0] = zero; acc[0][1] = zero; acc[1][0] = zero; acc[1][1] = zero;

    // mask sets: [0..1]=mf0/kf0, [2..3]=mf0/kf1, [4..5]=mf1/kf0, [6..7]=mf1/kf1
    float4 sA[8], sB[8], sC[8];
    // Vt sets: index kf*2+nf
    bf16x8 vA[4], vB[4], vC[4];

#define LOADSET(S, V, KS) {                                                   \
    const float* q0 = r0 + (size_t)(KS) * 64;                                 \
    const float* q1 = r1 + (size_t)(KS) * 64;                                 \
    S[0] = *(const float4*)(q0);      S[1] = *(const float4*)(q0 + 4);        \
    S[2] = *(const float4*)(q0 + 32); S[3] = *(const float4*)(q0 + 36);       \
    S[4] = *(const float4*)(q1);      S[5] = *(const float4*)(q1 + 4);        \
    S[6] = *(const float4*)(q1 + 32); S[7] = *(const float4*)(q1 + 36);       \
    const __bf16* qv = vb + (size_t)(KS) * 64;                                \
    V[0] = *(const bf16x8*)(qv);                                              \
    V[1] = *(const bf16x8*)(qv + (size_t)16 * 2048);                          \
    V[2] = *(const bf16x8*)(qv + 32);                                         \
    V[3] = *(const bf16x8*)(qv + (size_t)16 * 2048 + 32); }

#define COMPUTE(S, V) {                                                       \
    _Pragma("unroll")                                                         \
    for (int kf = 0; kf < 2; ++kf) {                                          \
        bf16x8 af0 = pack8(S[2 * kf],     S[2 * kf + 1]);                     \
        bf16x8 af1 = pack8(S[4 + 2 * kf], S[4 + 2 * kf + 1]);                 \
        _Pragma("unroll")                                                     \
        for (int nf = 0; nf < 2; ++nf) {                                      \
            acc[0][nf] = MFMA16(af0, V[kf * 2 + nf], acc[0][nf]);             \
            acc[1][nf] = MFMA16(af1, V[kf * 2 + nf], acc[1][nf]);             \
        }                                                                     \
    } }

    LOADSET(sA, vA, 0)
    LOADSET(sB, vB, 1)
    LOADSET(sC, vC, 2)
    for (int t = 0; t < 10; ++t) {
        const int ks = 3 * t;
        COMPUTE(sA, vA)
        LOADSET(sA, vA, ks + 3)                      // max 30, always valid
        COMPUTE(sB, vB)
        LOADSET(sB, vB, ks + 4)                      // max 31, always valid
        COMPUTE(sC, vC)
        if (ks + 5 < 32) LOADSET(sC, vC, ks + 5)     // skip only at t=9
    }
    COMPUTE(sA, vA)   // ks=30
    COMPUTE(sB, vB)   // ks=31
#undef LOADSET
#undef COMPUTE

    // epilogue: out = relu(acc + Ux)
    const size_t rowbase = (size_t)b * 2048 + m0;
    #pragma unroll
    for (int mf = 0; mf < 2; ++mf)
        #pragma unroll
        for (int nf = 0; nf < 2; ++nf) {
            const int e = wv * 32 + nf * 16 + l16;
            #pragma unroll
            for (int r = 0; r < 4; ++r) {
                const size_t row = rowbase + mf * 16 + l4 * 4 + r;
                const float v = acc[mf][nf][r] + (float)Uxb[row * 128 + e];
                out[row * 128 + e] = v > 0.f ? v : 0.f;
            }
        }
}

// ---------------------------------------------------------------------------
extern "C" void kernel_launch(void* const* d_in, const int* in_sizes, int n_in,
                              void* d_out, int out_size, void* d_ws, size_t ws_size,
                              hipStream_t stream) {
    (void)in_sizes; (void)n_in; (void)out_size; (void)ws_size;
    const float* x    = (const float*)d_in[0];   // [8][2048][128]
    const float* mask = (const float*)d_in[1];   // [8][2048][2048]
    const float* Wu   = (const float*)d_in[2];   // [128][128]
    const float* bu   = (const float*)d_in[3];   // [128]
    const float* Wv   = (const float*)d_in[4];   // [128][128]
    const float* bv   = (const float*)d_in[5];   // [128]
    float* out        = (float*)d_out;           // [8][2048][128] f32

    __bf16* Vt  = (__bf16*)d_ws;                 // [8][128][2048] bf16 (4MB)
    __bf16* Uxb = Vt + (size_t)8 * 128 * 2048;   // [16384][128]  bf16 (4MB)

    hipLaunchKernelGGL(k1_uv, dim3(256), dim3(256), 0, stream, x, Wu, bu, Wv, bv, Uxb, Vt);
    hipLaunchKernelGGL(k2_agg, dim3(512), dim3(256), 0, stream, mask, Vt, Uxb, out);
}

// Round 10
// 250.880 us; speedup vs baseline: 1.0908x; 1.0908x over previous
//
#include <hip/hip_runtime.h>

// NodeFeatures: out = relu(x@Wu^T + bu + mask @ (x@Wv^T + bv))
// B=8, N=2048, D=128.
// R7/R8: k2 ~112us, 9% HBM, MfmaUtil 3%, VGPR=124 -> compiler collapsed the
// register prefetch (loads sunk to uses). R9 (never ran): global_load_lds DMA
// staging (zero VGPR, can't be sunk) + 4 blocks/CU TLP. R9b fix found by
// static audit: R9's 32B-granule LDS swizzle only reached 2 bank bits ->
// 16-way conflicts. Now swizzle at 16B-chunk granularity (chunk ^= row&7):
// full 3-bit bank XOR -> 2-way (free, m136). Both sides same involution
// (rule #21): DMA source col pre-swizzled, read side XORs per 16B chunk.

typedef __bf16 bf16x8 __attribute__((ext_vector_type(8)));
typedef __bf16 bf16x4 __attribute__((ext_vector_type(4)));
typedef float  f32x4  __attribute__((ext_vector_type(4)));

#define MFMA16(A, B, C) __builtin_amdgcn_mfma_f32_16x16x32_bf16(A, B, C, 0, 0, 0)

static __device__ __forceinline__ bf16x8 cvt8(const float* __restrict__ p) {
    float4 a = *(const float4*)p;
    float4 b = *(const float4*)(p + 4);
    bf16x8 v;
    v[0] = (__bf16)a.x; v[1] = (__bf16)a.y; v[2] = (__bf16)a.z; v[3] = (__bf16)a.w;
    v[4] = (__bf16)b.x; v[5] = (__bf16)b.y; v[6] = (__bf16)b.z; v[7] = (__bf16)b.w;
    return v;
}

static __device__ __forceinline__ bf16x8 pack8(const float4 a, const float4 b) {
    bf16x8 v;
    v[0] = (__bf16)a.x; v[1] = (__bf16)a.y; v[2] = (__bf16)a.z; v[3] = (__bf16)a.w;
    v[4] = (__bf16)b.x; v[5] = (__bf16)b.y; v[6] = (__bf16)b.z; v[7] = (__bf16)b.w;
    return v;
}

static __device__ __forceinline__ void gload_lds16(const float* g, float* l) {
    __builtin_amdgcn_global_load_lds(
        (const __attribute__((address_space(1))) void*)g,
        (__attribute__((address_space(3))) void*)l, 16, 0, 0);
}

// ---------------------------------------------------------------------------
// Kernel 1 (unchanged): Uxb = bf16(x@Wu^T+bu); Vt[b][e][n] = bf16(x@Wv^T+bv)
// D-frag (m89-verified): col = lane&15, row = (lane>>4)*4 + reg.
// ---------------------------------------------------------------------------
__global__ __launch_bounds__(256) void k1_uv(
    const float* __restrict__ x,  const float* __restrict__ Wu,
    const float* __restrict__ bu, const float* __restrict__ Wv,
    const float* __restrict__ bv,
    __bf16* __restrict__ Uxb, __bf16* __restrict__ Vt)
{
    const int tid  = threadIdx.x;
    const int wv   = tid >> 6;
    const int lane = tid & 63;
    const int l16  = lane & 15;
    const int l4   = lane >> 4;
    const int row0 = blockIdx.x * 64;
    const int e0   = wv * 32;

    const f32x4 zero = {0.f, 0.f, 0.f, 0.f};
    f32x4 acc[4][4];
    #pragma unroll
    for (int mt = 0; mt < 4; ++mt)
        #pragma unroll
        for (int f = 0; f < 4; ++f) acc[mt][f] = zero;

    #pragma unroll
    for (int kf = 0; kf < 4; ++kf) {
        const int ko = kf * 32 + l4 * 8;
        bf16x8 af[4], bf[4];
        #pragma unroll
        for (int mt = 0; mt < 4; ++mt)
            af[mt] = cvt8(x + (size_t)(row0 + mt * 16 + l16) * 128 + ko);
        bf[0] = cvt8(Wu + (size_t)(e0 +      l16) * 128 + ko);
        bf[1] = cvt8(Wu + (size_t)(e0 + 16 + l16) * 128 + ko);
        bf[2] = cvt8(Wv + (size_t)(e0 +      l16) * 128 + ko);
        bf[3] = cvt8(Wv + (size_t)(e0 + 16 + l16) * 128 + ko);
        #pragma unroll
        for (int mt = 0; mt < 4; ++mt)
            #pragma unroll
            for (int f = 0; f < 4; ++f)
                acc[mt][f] = MFMA16(af[mt], bf[f], acc[mt][f]);
    }

    const int bidx = row0 >> 11;
    #pragma unroll
    for (int f = 0; f < 4; ++f) {
        const int e    = e0 + (f & 1) * 16 + l16;
        const bool isV = (f >= 2);
        const float bias = isV ? bv[e] : bu[e];
        #pragma unroll
        for (int mt = 0; mt < 4; ++mt) {
            if (!isV) {
                #pragma unroll
                for (int r = 0; r < 4; ++r) {
                    const int row = row0 + mt * 16 + l4 * 4 + r;
                    Uxb[(size_t)row * 128 + e] = (__bf16)(acc[mt][f][r] + bias);
                }
            } else {
                const int nbase = (row0 & 2047) + mt * 16 + l4 * 4;
                bf16x4 pk;
                #pragma unroll
                for (int r = 0; r < 4; ++r) pk[r] = (__bf16)(acc[mt][f][r] + bias);
                *(bf16x4*)(Vt + ((size_t)bidx * 128 + e) * 2048 + nbase) = pk;
            }
        }
    }
}

// ---------------------------------------------------------------------------
// Kernel 2 (R9b): BM=16, BK=128, 16 K-steps. Mask staged f32 via
// global_load_lds into double-buffered LDS (2 x 8KB), 16B-chunk XOR swizzle.
// Per step: issue 8 Vt loads (L2-hot) FIRST, then 2 DMA stages for ks+1
// (counted vmcnt: MFMA's Vt wait leaves the 2 newer DMAs in flight), then
// ds_read(swz)->cvt->8 MFMA, then __syncthreads (drains DMA).
// Grid 1024 = 8 XCD x 128 (batch-per-XCD); 4 blocks/CU -> 16 waves/CU.
// ---------------------------------------------------------------------------
__global__ __launch_bounds__(256) void k2_agg(
    const float* __restrict__ mask,
    const __bf16* __restrict__ Vt,
    const __bf16* __restrict__ Uxb,
    float* __restrict__ out)
{
    __shared__ float smem[2][16 * 128];   // 2 x 8KB f32 mask tile, swizzled

    const int bid = blockIdx.x;                    // 0..1023
    const int lb  = (bid & 7) * 128 + (bid >> 3);  // bijective XCD swizzle (1024=8*128)
    const int b   = lb >> 7;                       // batch (one batch per XCD)
    const int m0  = (lb & 127) * 16;               // row tile within batch

    const int tid  = threadIdx.x;
    const int wv   = tid >> 6;
    const int lane = tid & 63;
    const int l16  = lane & 15;
    const int l4   = lane >> 4;

    // --- DMA staging geometry: LDS dest linear (base + lane*16B); global
    // source pre-swizzled at 16B-chunk granularity so LDS chunk c of row r
    // holds global chunk c ^ (r&7). DMA0 -> rows wv*4+{0,1}, DMA1 -> +{2,3}.
    const int r_i0 = wv * 4 + (lane >> 5);
    const int r_i1 = r_i0 + 2;
    const int s4   = lane & 31;                   // 16B chunk within row
    const float* g0 = mask + ((size_t)b * 2048 + m0 + r_i0) * 2048
                           + (s4 ^ (r_i0 & 7)) * 4;
    const float* g1 = mask + ((size_t)b * 2048 + m0 + r_i1) * 2048
                           + (s4 ^ (r_i1 & 7)) * 4;

    // B operand base (Vt is [128e][2048n] per batch, L2-hot within the XCD)
    const __bf16* vb = Vt + ((size_t)b * 128 + wv * 32 + l16) * 2048 + l4 * 8;

    f32x4 acc[2];
    acc[0] = {0.f, 0.f, 0.f, 0.f};
    acc[1] = {0.f, 0.f, 0.f, 0.f};

#define STAGE(BUF, KS) {                                                      \
    gload_lds16(g0 + (size_t)(KS) * 128, &smem[BUF][wv * 512]);               \
    gload_lds16(g1 + (size_t)(KS) * 128, &smem[BUF][wv * 512 + 256]); }

    STAGE(0, 0)
    __syncthreads();

    #pragma unroll 2
    for (int ks = 0; ks < 16; ++ks) {
        const int cur = ks & 1;
        // Vt fragments for THIS step — issued first so the MFMA wait is a
        // counted vmcnt (the 2 DMAs below stay outstanding across it).
        bf16x8 V[8];
        {
            const __bf16* q = vb + (size_t)ks * 128;
            V[0] = *(const bf16x8*)(q);
            V[1] = *(const bf16x8*)(q + (size_t)16 * 2048);
            V[2] = *(const bf16x8*)(q + 32);
            V[3] = *(const bf16x8*)(q + (size_t)16 * 2048 + 32);
            V[4] = *(const bf16x8*)(q + 64);
            V[5] = *(const bf16x8*)(q + (size_t)16 * 2048 + 64);
            V[6] = *(const bf16x8*)(q + 96);
            V[7] = *(const bf16x8*)(q + (size_t)16 * 2048 + 96);
        }
        if (ks + 1 < 16) STAGE(cur ^ 1, ks + 1)
        #pragma unroll
        for (int kf = 0; kf < 4; ++kf) {
            // logical 16B chunks q2, q2+1 of row l16; phys = chunk ^ (row&7)
            const int q2 = (kf * 4 + l4) * 2;
            const int p0 = (q2       ^ (l16 & 7)) * 4;
            const int p1 = ((q2 + 1) ^ (l16 & 7)) * 4;
            bf16x8 af = pack8(*(const float4*)&smem[cur][l16 * 128 + p0],
                              *(const float4*)&smem[cur][l16 * 128 + p1]);
            acc[0] = MFMA16(af, V[kf * 2],     acc[0]);
            acc[1] = MFMA16(af, V[kf * 2 + 1], acc[1]);
        }
        __syncthreads();
    }
#undef STAGE

    // epilogue: out = relu(acc + Ux); D-frag: col=l16, row=l4*4+reg
    const size_t rowbase = (size_t)b * 2048 + m0;
    #pragma unroll
    for (int nf = 0; nf < 2; ++nf) {
        const int e = wv * 32 + nf * 16 + l16;
        #pragma unroll
        for (int r = 0; r < 4; ++r) {
            const size_t row = rowbase + l4 * 4 + r;
            const float v = acc[nf][r] + (float)Uxb[row * 128 + e];
            out[row * 128 + e] = v > 0.f ? v : 0.f;
        }
    }
}

// ---------------------------------------------------------------------------
extern "C" void kernel_launch(void* const* d_in, const int* in_sizes, int n_in,
                              void* d_out, int out_size, void* d_ws, size_t ws_size,
                              hipStream_t stream) {
    (void)in_sizes; (void)n_in; (void)out_size; (void)ws_size;
    const float* x    = (const float*)d_in[0];   // [8][2048][128]
    const float* mask = (const float*)d_in[1];   // [8][2048][2048]
    const float* Wu   = (const float*)d_in[2];   // [128][128]
    const float* bu   = (const float*)d_in[3];   // [128]
    const float* Wv   = (const float*)d_in[4];   // [128][128]
    const float* bv   = (const float*)d_in[5];   // [128]
    float* out        = (float*)d_out;           // [8][2048][128] f32

    __bf16* Vt  = (__bf16*)d_ws;                 // [8][128][2048] bf16 (4MB)
    __bf16* Uxb = Vt + (size_t)8 * 128 * 2048;   // [16384][128]  bf16 (4MB)

    hipLaunchKernelGGL(k1_uv, dim3(256), dim3(256), 0, stream, x, Wu, bu, Wv, bv, Uxb, Vt);
    hipLaunchKernelGGL(k2_agg, dim3(1024), dim3(256), 0, stream, mask, Vt, Uxb, out);
}